// Round 17
// baseline (746.632 us; speedup 1.0000x reference)
//
#include <hip/hip_runtime.h>
#include <math.h>

#define N_NODES 50000
#define N_EDGES 1600000
#define IN_CH 32
#define HID 64

// ---------------- pipeline (8 dispatches, zero global atomics) -------------
// prep(hist+wprep+xconv fused) -> scan(3) -> partition -> bindeg -> fgather
//   -> dense(MFMA)
// Round-17: fgather rewritten EDGE-PARALLEL with in-LDS atomic accumulation:
// no per-bin sort (phases A/B gone), no per-node list walk -- the old scheme
// ran each wave at the MAX of its 8 groups' Poisson(32) list lengths (~35%
// wasted lanes). s_acc[64][33] fp32 (stride 33 -> random ~2-way bank
// aliasing, free per m136); uniform slot loop, 2-way unrolled. bindeg loses
// the count accumulation (fgather no longer needs binCnt).
#define NBIN 782
#define BIN_SHIFT 6
#define CHUNK 8192
#define NCHK ((N_EDGES + CHUNK - 1) / CHUNK)   // 196
#define CNTG_N (2 * NBIN * NCHK)               // 306544 (divisible by 4)
#define CNTG_N4 (CNTG_N / 4)                   // 76636
#define SCAN_BLOCKS ((CNTG_N4 + 1023) / 1024)  // 75

#define PREP_WPREP_BLOCKS 48
#define PREP_XCONV_BLOCKS ((N_NODES * 8 + 255) / 256)  // 1563
#define PREP_BLOCKS (NCHK + PREP_WPREP_BLOCKS + PREP_XCONV_BLOCKS)  // 1807

// ---------------- workspace layout (int element offsets into d_ws)
#define WS_RDEG_OUT 0          // 50000 f (row-degree reciprocals, from dir1 bins)
#define WS_RDEG_IN  50000      // 50000 f (col-degree reciprocals, from dir0 bins)
#define WS_CNTG     100000     // 306544 i ((dir,bin,chunk) counts; scanned in place)
#define WS_BLKSUM   406548     // 128 i
#define WS_WBF      406676     // 6144 i = 12288 ushort (bf16 weights, B-frag order)
#define WS_XSB      412820     // 800000 i = 1.6M ushort (bf16 x, unscaled)
#define WS_TXO      1212820    // 800000 i (bf16 Tx_o, 50000 x 32)
#define WS_TXI      2012820    // 800000 i (bf16 Tx_i)
#define WS_BINNED   2812820    // int2[3.2M] = 6400000 i
#define WS_END      9212820    // 36.9 MB (ws is 256 MiB)

typedef __attribute__((ext_vector_type(8))) short bf16x8;
typedef __attribute__((ext_vector_type(4))) float f32x4;

__device__ __forceinline__ unsigned short f2bf(float f) {  // RNE fp32 -> bf16
    unsigned int u = __float_as_uint(f);
    return (unsigned short)((u + 0x7fffu + ((u >> 16) & 1u)) >> 16);
}
__device__ __forceinline__ float bf2f(unsigned short b) {
    return __uint_as_float((unsigned int)b << 16);
}

// 0. fused prep: block-role split (hist first: feeds the scan critical path).
__global__ __launch_bounds__(256) void prep_kernel(
    const int* __restrict__ ei, const float* __restrict__ Wz,
    const float* __restrict__ Wh, const float4* __restrict__ x4,
    int* __restrict__ cntG, unsigned short* __restrict__ wbf,
    ushort4* __restrict__ xsb) {
    __shared__ int h[2 * NBIN];
    int tid = threadIdx.x;
    int b = blockIdx.x;
    if (b < NCHK) {  // hist role
        for (int i = tid; i < 2 * NBIN; i += 256) h[i] = 0;
        __syncthreads();
        int e0 = b * CHUNK;
        int e1 = min(e0 + CHUNK, N_EDGES);
        for (int e = e0 + tid; e < e1; e += 256) {
            int r = ei[e];
            int c = ei[N_EDGES + e];
            atomicAdd(&h[c >> BIN_SHIFT], 1);           // dir0: group by col
            atomicAdd(&h[NBIN + (r >> BIN_SHIFT)], 1);  // dir1: group by row
        }
        __syncthreads();
        for (int i = tid; i < 2 * NBIN; i += 256) cntG[i * NCHK + b] = h[i];
    } else if (b < NCHK + PREP_WPREP_BLOCKS) {  // wprep role (B-frag order)
        int idx = (b - NCHK) * 256 + tid;
        if (idx >= 12288) return;
        int j = idx & 7, ln = (idx >> 3) & 63, bn = (idx >> 9) & 7, kk = idx >> 12;
        int k = kk * 32 + (ln >> 4) * 8 + j;
        int n = bn * 16 + (ln & 15);
        int slab = k >> 5, c = k & 31;
        const float* W = (n < 64) ? Wz : Wh;
        int o = n & 63;
        float v;
        if (slab == 0)      v = W[c * 64 + o] + W[(2 * 96 + c) * 64 + o];
        else if (slab == 1) v = W[(96 + c) * 64 + o];
        else                v = W[(3 * 96 + c) * 64 + o];
        wbf[idx] = f2bf(v);
    } else {  // xconv role
        int i = (b - NCHK - PREP_WPREP_BLOCKS) * 256 + tid;
        if (i >= N_NODES * 8) return;
        float4 v = x4[i];
        ushort4 o;
        o.x = f2bf(v.x); o.y = f2bf(v.y); o.z = f2bf(v.z); o.w = f2bf(v.w);
        xsb[i] = o;
    }
}

// ---- 3-phase exclusive scan over cntG ----
__global__ __launch_bounds__(256) void scan_partial_kernel(
    const int4* __restrict__ cnt4, int* __restrict__ blksum, int n4) {
    __shared__ int s[256];
    int t = threadIdx.x;
    int base4 = blockIdx.x * 1024 + t * 4;
    int total = 0;
#pragma unroll
    for (int j = 0; j < 4; ++j) {
        int idx = base4 + j;
        if (idx < n4) {
            int4 v = cnt4[idx];
            total += v.x + v.y + v.z + v.w;
        }
    }
    s[t] = total;
    __syncthreads();
    for (int off = 128; off > 0; off >>= 1) {
        if (t < off) s[t] += s[t + off];
        __syncthreads();
    }
    if (t == 0) blksum[blockIdx.x] = s[0];
}

__global__ __launch_bounds__(256) void scan_blocksum_kernel(int* __restrict__ blksum, int nb) {
    __shared__ int s[256];
    int t = threadIdx.x;
    int v = (t < nb) ? blksum[t] : 0;
    s[t] = v;
    __syncthreads();
    for (int off = 1; off < 256; off <<= 1) {
        int u = (t >= off) ? s[t - off] : 0;
        __syncthreads();
        s[t] += u;
        __syncthreads();
    }
    if (t < nb) blksum[t] = s[t] - v;  // exclusive
}

__global__ __launch_bounds__(256) void scan_final_kernel(
    int4* __restrict__ cnt4, const int* __restrict__ blksum, int n4) {
    __shared__ int s[256];
    int t = threadIdx.x;
    int base4 = blockIdx.x * 1024 + t * 4;
    int4 vals[4];
    int total = 0;
#pragma unroll
    for (int j = 0; j < 4; ++j) {
        int idx = base4 + j;
        vals[j] = (idx < n4) ? cnt4[idx] : make_int4(0, 0, 0, 0);
        total += vals[j].x + vals[j].y + vals[j].z + vals[j].w;
    }
    s[t] = total;
    __syncthreads();
    for (int off = 1; off < 256; off <<= 1) {
        int u = (t >= off) ? s[t - off] : 0;
        __syncthreads();
        s[t] += u;
        __syncthreads();
    }
    int run = blksum[blockIdx.x] + s[t] - total;
#pragma unroll
    for (int j = 0; j < 4; ++j) {
        int idx = base4 + j;
        int4 v = vals[j];
        int4 o;
        o.x = run; run += v.x;
        o.y = run; run += v.y;
        o.z = run; run += v.z;
        o.w = run; run += v.w;
        if (idx < n4) cnt4[idx] = o;
    }
}

// 3. COALESCED partition. One block = one (dir, chunk of 8192); LDS
// re-staging makes the global write-out coalesced (runs ~10.4 edges).
__global__ __launch_bounds__(512) void partition_kernel(
    const int* __restrict__ ei, const float* __restrict__ ew,
    const int* __restrict__ cntG, int2* __restrict__ binned) {
    __shared__ int2 stg[CHUNK];      // 64 KB
    __shared__ int hist[NBIN];
    __shared__ int lst[NBIN];        // local bin starts
    __shared__ int gStart[NBIN];
    __shared__ int sc[512];
    int tid = threadIdx.x;
    int dir = (blockIdx.x >= NCHK) ? 1 : 0;
    int chunk = blockIdx.x - dir * NCHK;

    for (int i = tid; i < NBIN; i += 512) hist[i] = 0;
    __syncthreads();

    int e0 = chunk * CHUNK;
    int n_e = min(CHUNK, N_EDGES - e0);
    int binv[16], rankv[16];
    int2 pay[16];
#pragma unroll
    for (int j = 0; j < 16; ++j) {
        int idx = tid + j * 512;
        if (idx < n_e) {
            int e = e0 + idx;
            int r = ei[e];
            int c = ei[N_EDGES + e];
            int dst = dir ? r : c;
            int src = dir ? c : r;
            int b = dst >> BIN_SHIFT;
            binv[j] = b;
            rankv[j] = atomicAdd(&hist[b], 1);
            pay[j] = make_int2((int)(((unsigned)b << 22) | ((unsigned)(dst & 63) << 16) |
                                     (unsigned)src),
                               __float_as_int(ew[e]));
        } else {
            binv[j] = -1;
        }
    }
    __syncthreads();
    // pair-scan: 391 pairs cover 782 bins
    int ps = (tid < 391) ? (hist[2 * tid] + hist[2 * tid + 1]) : 0;
    sc[tid] = ps;
    __syncthreads();
    for (int off = 1; off < 512; off <<= 1) {
        int u = (tid >= off) ? sc[tid - off] : 0;
        __syncthreads();
        sc[tid] += u;
        __syncthreads();
    }
    if (tid < 391) {
        int pref = sc[tid] - ps;  // exclusive pair prefix
        lst[2 * tid] = pref;
        lst[2 * tid + 1] = pref + hist[2 * tid];
    }
    for (int i = tid; i < NBIN; i += 512)
        gStart[i] = cntG[(dir * NBIN + i) * NCHK + chunk];
    __syncthreads();
#pragma unroll
    for (int j = 0; j < 16; ++j)
        if (binv[j] >= 0) stg[lst[binv[j]] + rankv[j]] = pay[j];
    __syncthreads();
    for (int p = tid; p < n_e; p += 512) {
        int2 v2 = stg[p];
        int b = (int)(((unsigned)v2.x) >> 22);
        int gpos = gStart[b] + (p - lst[b]);
        binned[gpos] = make_int2(v2.x & 0x3FFFFF, v2.y);
    }
}

__device__ __forceinline__ void bin_range(const int* cntG, int b, int& lo, int& hi) {
    lo = cntG[b * NCHK];
    hi = (b + 1 < 2 * NBIN) ? cntG[(b + 1) * NCHK] : 2 * N_EDGES;
}

// 4. per-bin degrees (both dirs, one launch); linear stream; 1 LDS atomic/edge
// (round-17: count accumulation dropped -- fgather no longer needs it).
__global__ __launch_bounds__(256) void bindeg_kernel(
    const int* __restrict__ cntG, const int2* __restrict__ binned,
    float* __restrict__ ws_f) {
    __shared__ float wsum[64];
    int tid = threadIdx.x;
    int b = blockIdx.x;
    int dir = (b >= NBIN) ? 1 : 0;
    if (tid < 64) wsum[tid] = 0.f;
    __syncthreads();
    int lo, hi;
    bin_range(cntG, b, lo, hi);
    for (int p = lo + tid; p < hi; p += 256) {
        int2 v = binned[p];
        atomicAdd(&wsum[v.x >> 16], __int_as_float(v.y));
    }
    __syncthreads();
    if (tid < 64) {
        int node = (b - dir * NBIN) * 64 + tid;
        if (node < N_NODES) {
            float s = wsum[tid];
            float* rdeg = ws_f + (dir == 0 ? WS_RDEG_IN : WS_RDEG_OUT);
            rdeg[node] = (s != 0.f) ? (1.f / s) : 0.f;
        }
    }
}

// 5. EDGE-PARALLEL fgather: no sort, no list walk. 32 slots x 8 lanes; each
// slot streams edges strided by 32 (uniform work -- no Poisson-max
// divergence), 2-way unrolled for gather MLP. Accumulate via LDS fp32
// atomics into s_acc[64][33] (stride 33: bank = dst + 4*lane + j mod 32,
// random dst => ~2-way aliasing, free). Write out bf16.
#define FG_STRIDE 33
__global__ __launch_bounds__(256) void fgather_kernel(
    const ushort4* __restrict__ xsb, const int* __restrict__ cntG,
    const int2* __restrict__ binned, float* __restrict__ ws_f) {
    __shared__ float s_acc[64 * FG_STRIDE];  // 8.25 KB
    int tid = threadIdx.x;
    int b = blockIdx.x;
    int dir = (b >= NBIN) ? 1 : 0;
    int bin = b - dir * NBIN;
    for (int i = tid; i < 64 * FG_STRIDE; i += 256) s_acc[i] = 0.f;
    const float* rdeg = ws_f + (dir == 0 ? WS_RDEG_OUT : WS_RDEG_IN);
    __syncthreads();

    int lo, hi;
    bin_range(cntG, b, lo, hi);
    int lane = tid & 7;
    int slot = tid >> 3;  // 0..31
    int p = lo + slot;
    for (; p + 32 < hi; p += 64) {  // 2 edges per slot iteration
        int2 e0 = binned[p];
        int2 e1 = binned[p + 32];
        int s0 = e0.x & 0xffff, s1 = e1.x & 0xffff;
        ushort4 a0 = xsb[s0 * 8 + lane];
        ushort4 a1 = xsb[s1 * 8 + lane];
        float c0 = __int_as_float(e0.y) * rdeg[s0];
        float c1 = __int_as_float(e1.y) * rdeg[s1];
        float* q0 = &s_acc[(e0.x >> 16) * FG_STRIDE + lane * 4];
        float* q1 = &s_acc[(e1.x >> 16) * FG_STRIDE + lane * 4];
        atomicAdd(&q0[0], c0 * bf2f(a0.x));
        atomicAdd(&q0[1], c0 * bf2f(a0.y));
        atomicAdd(&q0[2], c0 * bf2f(a0.z));
        atomicAdd(&q0[3], c0 * bf2f(a0.w));
        atomicAdd(&q1[0], c1 * bf2f(a1.x));
        atomicAdd(&q1[1], c1 * bf2f(a1.y));
        atomicAdd(&q1[2], c1 * bf2f(a1.z));
        atomicAdd(&q1[3], c1 * bf2f(a1.w));
    }
    if (p < hi) {
        int2 e0 = binned[p];
        int s0 = e0.x & 0xffff;
        ushort4 a0 = xsb[s0 * 8 + lane];
        float c0 = __int_as_float(e0.y) * rdeg[s0];
        float* q0 = &s_acc[(e0.x >> 16) * FG_STRIDE + lane * 4];
        atomicAdd(&q0[0], c0 * bf2f(a0.x));
        atomicAdd(&q0[1], c0 * bf2f(a0.y));
        atomicAdd(&q0[2], c0 * bf2f(a0.z));
        atomicAdd(&q0[3], c0 * bf2f(a0.w));
    }
    __syncthreads();

    // write out 64 nodes x 32 ch as bf16
    ushort4* outp = (ushort4*)(ws_f + (dir == 0 ? WS_TXO : WS_TXI));
    for (int idx = tid; idx < 64 * 8; idx += 256) {
        int nl = idx >> 3, q = idx & 7;
        int node = bin * 64 + nl;
        if (node < N_NODES) {
            const float* ap = &s_acc[nl * FG_STRIDE + q * 4];
            ushort4 o;
            o.x = f2bf(ap[0]); o.y = f2bf(ap[1]);
            o.z = f2bf(ap[2]); o.w = f2bf(ap[3]);
            outp[node * 8 + q] = o;
        }
    }
}

// 6. Dense epilogue via bf16 MFMA (unchanged from round 16).
// Per block: C[64 x 128 (z|h)] = A[64x96]_bf16 x B[96x128]_bf16 + bias.
// A-frag: A[m=lane&15][k=quad*8+j]; B-frag: B[k=quad*8+j][n=lane&15];
// C/D: col=lane&15, row=quad*4+reg (m89/m91-verified).
#define DN_GROUP 64
#define DN_BLOCKS ((N_NODES + DN_GROUP - 1) / DN_GROUP)  // 782
__global__ __launch_bounds__(256) void dense_kernel(
    const int4* __restrict__ xsb4,
    const int4* __restrict__ txo_b, const int4* __restrict__ txi_b,
    const unsigned short* __restrict__ wbf,
    const float* __restrict__ bz, const float* __restrict__ bh,
    const float* __restrict__ Wlin, const float* __restrict__ blin,
    float* __restrict__ out) {
    __shared__ unsigned short sA[64 * 104];  // 13.0 KB
    __shared__ unsigned short sB[12288];     // 24.0 KB

    int tid = threadIdx.x;
    int lane = tid & 63, w = tid >> 6;
    int lm = lane & 15, quad = lane >> 4;

    for (int idx = tid; idx < 3072; idx += 256)
        *(ushort4*)&sB[idx * 4] = ((const ushort4*)wbf)[idx];

    int node0 = blockIdx.x * DN_GROUP;
    for (int idx = tid; idx < 64 * 4; idx += 256) {
        int nl = idx >> 2, q = idx & 3;
        int node = node0 + nl;
        int4 v = (node < N_NODES) ? xsb4[node * 4 + q] : make_int4(0, 0, 0, 0);
        *(int4*)&sA[nl * 104 + q * 8] = v;
    }
    for (int idx = tid; idx < 64 * 8; idx += 256) {
        int nl = idx >> 3, q = idx & 7;
        int node = node0 + nl;
        int4 v = make_int4(0, 0, 0, 0);
        if (node < N_NODES)
            v = (q < 4) ? txo_b[node * 4 + q] : txi_b[node * 4 + (q - 4)];
        *(int4*)&sA[nl * 104 + 32 + q * 8] = v;
    }

    float bzv[4], bhv[4], wlv[4];
#pragma unroll
    for (int bn = 0; bn < 4; ++bn) {
        int o = lm + 16 * bn;
        bzv[bn] = bz[o]; bhv[bn] = bh[o]; wlv[bn] = Wlin[o];
    }
    float bl = blin[0];
    __syncthreads();

    f32x4 acc[8];
#pragma unroll
    for (int bn = 0; bn < 4; ++bn) {
        acc[bn]     = (f32x4){bzv[bn], bzv[bn], bzv[bn], bzv[bn]};
        acc[bn + 4] = (f32x4){bhv[bn], bhv[bn], bhv[bn], bhv[bn]};
    }
#pragma unroll
    for (int kk = 0; kk < 3; ++kk) {
        bf16x8 af = *(const bf16x8*)&sA[(w * 16 + lm) * 104 + kk * 32 + quad * 8];
#pragma unroll
        for (int bn = 0; bn < 8; ++bn) {
            bf16x8 bf = *(const bf16x8*)&sB[((kk * 8 + bn) * 64 + lane) * 8];
            acc[bn] = __builtin_amdgcn_mfma_f32_16x16x32_bf16(af, bf, acc[bn], 0, 0, 0);
        }
    }

    float partial[4] = {0.f, 0.f, 0.f, 0.f};
#pragma unroll
    for (int bn = 0; bn < 4; ++bn) {
#pragma unroll
        for (int reg = 0; reg < 4; ++reg) {
            float az = acc[bn][reg], ah = acc[bn + 4][reg];
            float z = 1.f / (1.f + __expf(-az));
            float ht = 1.f - 2.f / (__expf(2.f * ah) + 1.f);
            partial[reg] += fmaxf((1.f - z) * ht, 0.f) * wlv[bn];
        }
    }
#pragma unroll
    for (int reg = 0; reg < 4; ++reg) {
        float s = partial[reg];
        s += __shfl_xor(s, 1, 64);
        s += __shfl_xor(s, 2, 64);
        s += __shfl_xor(s, 4, 64);
        s += __shfl_xor(s, 8, 64);
        if (lm == 0) {
            int node = node0 + w * 16 + quad * 4 + reg;
            if (node < N_NODES) out[node] = s + bl;
        }
    }
}

extern "C" void kernel_launch(void* const* d_in, const int* in_sizes, int n_in,
                              void* d_out, int out_size, void* d_ws, size_t ws_size,
                              hipStream_t stream) {
    const float* x = (const float*)d_in[0];
    const int* ei = (const int*)d_in[1];
    const float* ew = (const float*)d_in[2];
    const float* Wz = (const float*)d_in[3];
    const float* bz = (const float*)d_in[4];
    // d_in[5]=Wr, d_in[6]=br dead: H0==0 makes the reset gate a no-op
    const float* Wh = (const float*)d_in[7];
    const float* bh = (const float*)d_in[8];
    const float* Wlin = (const float*)d_in[9];
    const float* blin = (const float*)d_in[10];
    float* out = (float*)d_out;
    float* wf = (float*)d_ws;
    int* wi = (int*)d_ws;
    int2* binned = (int2*)(wi + WS_BINNED);

    // 0. fused prep: hist (chunks, critical path) + wprep + xconv
    prep_kernel<<<PREP_BLOCKS, 256, 0, stream>>>(
        ei, Wz, Wh, (const float4*)x, wi + WS_CNTG,
        (unsigned short*)(wi + WS_WBF), (ushort4*)(wi + WS_XSB));
    // 1. exclusive scan of the (dir,bin,chunk) count matrix
    scan_partial_kernel<<<SCAN_BLOCKS, 256, 0, stream>>>(
        (const int4*)(wi + WS_CNTG), wi + WS_BLKSUM, CNTG_N4);
    scan_blocksum_kernel<<<1, 256, 0, stream>>>(wi + WS_BLKSUM, SCAN_BLOCKS);
    scan_final_kernel<<<SCAN_BLOCKS, 256, 0, stream>>>(
        (int4*)(wi + WS_CNTG), wi + WS_BLKSUM, CNTG_N4);
    // 2. coalesced partition (one block per dir x 8192-chunk; LDS re-staging)
    partition_kernel<<<2 * NCHK, 512, 0, stream>>>(ei, ew, wi + WS_CNTG, binned);
    // 3. per-bin degrees (both dirs, linear stream, 1 LDS atomic/edge)
    bindeg_kernel<<<2 * NBIN, 256, 0, stream>>>(wi + WS_CNTG, binned, wf);
    // 4. edge-parallel fgather, both dirs -> bf16 Tx_o / Tx_i
    fgather_kernel<<<2 * NBIN, 256, 0, stream>>>(
        (const ushort4*)(wi + WS_XSB), wi + WS_CNTG, binned, wf);
    // 5. MFMA dense epilogue (all-bf16 inputs)
    dense_kernel<<<DN_BLOCKS, 256, 0, stream>>>(
        (const int4*)(wi + WS_XSB), (const int4*)(wi + WS_TXO),
        (const int4*)(wi + WS_TXI), (const unsigned short*)(wi + WS_WBF),
        bz, bh, Wlin, blin, out);
}

// Round 18
// 196.303 us; speedup vs baseline: 3.8035x; 3.8035x over previous
//
#include <hip/hip_runtime.h>
#include <math.h>

#define N_NODES 50000
#define N_EDGES 1600000
#define IN_CH 32
#define HID 64

// ---------------- pipeline (8 dispatches, zero global atomics) -------------
// prep(hist+wprep+xconv fused) -> scan(3) -> partition -> bindeg -> fgather
//   -> dense(MFMA)
// Round-18: FULL REVERT to round-16 (best known, 195.6 us). Round-17's
// edge-parallel fgather with LDS fp32 atomicAdd ran 13x slower: 102M LDS
// float atomics serialize (~5-6 ns/op, VALUBusy 2%, conflicts 0 -- RMW
// path, not a banked access). LESSON: never put LDS fp32 atomics on a
// per-edge inner loop; the sorted-list walk is the right structure.
#define NBIN 782
#define BIN_SHIFT 6
#define CHUNK 8192
#define NCHK ((N_EDGES + CHUNK - 1) / CHUNK)   // 196
#define CNTG_N (2 * NBIN * NCHK)               // 306544 (divisible by 4)
#define CNTG_N4 (CNTG_N / 4)                   // 76636
#define SCAN_BLOCKS ((CNTG_N4 + 1023) / 1024)  // 75
#define FG_CAP 2560   // bin capacity: mean 2046 + ~11 sigma (Binomial)

#define PREP_WPREP_BLOCKS 48
#define PREP_XCONV_BLOCKS ((N_NODES * 8 + 255) / 256)  // 1563
#define PREP_BLOCKS (NCHK + PREP_WPREP_BLOCKS + PREP_XCONV_BLOCKS)  // 1807

// ---------------- workspace layout (int element offsets into d_ws)
#define WS_RDEG_OUT 0          // 50000 f (row-degree reciprocals, from dir1 bins)
#define WS_RDEG_IN  50000      // 50000 f (col-degree reciprocals, from dir0 bins)
#define WS_CNTG     100000     // 306544 i ((dir,bin,chunk) counts; scanned in place)
#define WS_BLKSUM   406548     // 128 i
#define WS_WBF      406676     // 6144 i = 12288 ushort (bf16 weights, B-frag order)
#define WS_BINCNT   412820     // 100096 i (1564 bins x 64 per-node counts)
#define WS_XSB      512916     // 800000 i = 1.6M ushort (bf16 x, unscaled)
#define WS_TXO      1312916    // 800000 i (bf16 Tx_o, 50000 x 32)
#define WS_TXI      2112916    // 800000 i (bf16 Tx_i)
#define WS_BINNED   2912916    // int2[3.2M] = 6400000 i
#define WS_END      9312916    // 37.3 MB (ws is 256 MiB)

typedef __attribute__((ext_vector_type(8))) short bf16x8;
typedef __attribute__((ext_vector_type(4))) float f32x4;

__device__ __forceinline__ unsigned short f2bf(float f) {  // RNE fp32 -> bf16
    unsigned int u = __float_as_uint(f);
    return (unsigned short)((u + 0x7fffu + ((u >> 16) & 1u)) >> 16);
}
__device__ __forceinline__ float bf2f(unsigned short b) {
    return __uint_as_float((unsigned int)b << 16);
}

// 0. fused prep: block-role split (hist first: feeds the scan critical path).
// B-frag order: idx = ((kk*8+bn)*64+lane)*8+j holds
// Bmat[k=kk*32+(lane>>4)*8+j][n=bn*16+(lane&15)], Bmat = [Wz_eff | Wh_eff].
__global__ __launch_bounds__(256) void prep_kernel(
    const int* __restrict__ ei, const float* __restrict__ Wz,
    const float* __restrict__ Wh, const float4* __restrict__ x4,
    int* __restrict__ cntG, unsigned short* __restrict__ wbf,
    ushort4* __restrict__ xsb) {
    __shared__ int h[2 * NBIN];
    int tid = threadIdx.x;
    int b = blockIdx.x;
    if (b < NCHK) {  // hist role
        for (int i = tid; i < 2 * NBIN; i += 256) h[i] = 0;
        __syncthreads();
        int e0 = b * CHUNK;
        int e1 = min(e0 + CHUNK, N_EDGES);
        for (int e = e0 + tid; e < e1; e += 256) {
            int r = ei[e];
            int c = ei[N_EDGES + e];
            atomicAdd(&h[c >> BIN_SHIFT], 1);           // dir0: group by col
            atomicAdd(&h[NBIN + (r >> BIN_SHIFT)], 1);  // dir1: group by row
        }
        __syncthreads();
        for (int i = tid; i < 2 * NBIN; i += 256) cntG[i * NCHK + b] = h[i];
    } else if (b < NCHK + PREP_WPREP_BLOCKS) {  // wprep role
        int idx = (b - NCHK) * 256 + tid;
        if (idx >= 12288) return;
        int j = idx & 7, ln = (idx >> 3) & 63, bn = (idx >> 9) & 7, kk = idx >> 12;
        int k = kk * 32 + (ln >> 4) * 8 + j;
        int n = bn * 16 + (ln & 15);
        int slab = k >> 5, c = k & 31;
        const float* W = (n < 64) ? Wz : Wh;
        int o = n & 63;
        float v;
        if (slab == 0)      v = W[c * 64 + o] + W[(2 * 96 + c) * 64 + o];
        else if (slab == 1) v = W[(96 + c) * 64 + o];
        else                v = W[(3 * 96 + c) * 64 + o];
        wbf[idx] = f2bf(v);
    } else {  // xconv role
        int i = (b - NCHK - PREP_WPREP_BLOCKS) * 256 + tid;
        if (i >= N_NODES * 8) return;
        float4 v = x4[i];
        ushort4 o;
        o.x = f2bf(v.x); o.y = f2bf(v.y); o.z = f2bf(v.z); o.w = f2bf(v.w);
        xsb[i] = o;
    }
}

// ---- 3-phase exclusive scan over cntG ----
__global__ __launch_bounds__(256) void scan_partial_kernel(
    const int4* __restrict__ cnt4, int* __restrict__ blksum, int n4) {
    __shared__ int s[256];
    int t = threadIdx.x;
    int base4 = blockIdx.x * 1024 + t * 4;
    int total = 0;
#pragma unroll
    for (int j = 0; j < 4; ++j) {
        int idx = base4 + j;
        if (idx < n4) {
            int4 v = cnt4[idx];
            total += v.x + v.y + v.z + v.w;
        }
    }
    s[t] = total;
    __syncthreads();
    for (int off = 128; off > 0; off >>= 1) {
        if (t < off) s[t] += s[t + off];
        __syncthreads();
    }
    if (t == 0) blksum[blockIdx.x] = s[0];
}

__global__ __launch_bounds__(256) void scan_blocksum_kernel(int* __restrict__ blksum, int nb) {
    __shared__ int s[256];
    int t = threadIdx.x;
    int v = (t < nb) ? blksum[t] : 0;
    s[t] = v;
    __syncthreads();
    for (int off = 1; off < 256; off <<= 1) {
        int u = (t >= off) ? s[t - off] : 0;
        __syncthreads();
        s[t] += u;
        __syncthreads();
    }
    if (t < nb) blksum[t] = s[t] - v;  // exclusive
}

__global__ __launch_bounds__(256) void scan_final_kernel(
    int4* __restrict__ cnt4, const int* __restrict__ blksum, int n4) {
    __shared__ int s[256];
    int t = threadIdx.x;
    int base4 = blockIdx.x * 1024 + t * 4;
    int4 vals[4];
    int total = 0;
#pragma unroll
    for (int j = 0; j < 4; ++j) {
        int idx = base4 + j;
        vals[j] = (idx < n4) ? cnt4[idx] : make_int4(0, 0, 0, 0);
        total += vals[j].x + vals[j].y + vals[j].z + vals[j].w;
    }
    s[t] = total;
    __syncthreads();
    for (int off = 1; off < 256; off <<= 1) {
        int u = (t >= off) ? s[t - off] : 0;
        __syncthreads();
        s[t] += u;
        __syncthreads();
    }
    int run = blksum[blockIdx.x] + s[t] - total;
#pragma unroll
    for (int j = 0; j < 4; ++j) {
        int idx = base4 + j;
        int4 v = vals[j];
        int4 o;
        o.x = run; run += v.x;
        o.y = run; run += v.y;
        o.z = run; run += v.z;
        o.w = run; run += v.w;
        if (idx < n4) cnt4[idx] = o;
    }
}

// 2. COALESCED partition. One block = one (dir, chunk of 8192); LDS
// re-staging makes the global write-out coalesced (runs ~10.4 edges).
__global__ __launch_bounds__(512) void partition_kernel(
    const int* __restrict__ ei, const float* __restrict__ ew,
    const int* __restrict__ cntG, int2* __restrict__ binned) {
    __shared__ int2 stg[CHUNK];      // 64 KB
    __shared__ int hist[NBIN];
    __shared__ int lst[NBIN];        // local bin starts
    __shared__ int gStart[NBIN];
    __shared__ int sc[512];
    int tid = threadIdx.x;
    int dir = (blockIdx.x >= NCHK) ? 1 : 0;
    int chunk = blockIdx.x - dir * NCHK;

    for (int i = tid; i < NBIN; i += 512) hist[i] = 0;
    __syncthreads();

    int e0 = chunk * CHUNK;
    int n_e = min(CHUNK, N_EDGES - e0);
    int binv[16], rankv[16];
    int2 pay[16];
#pragma unroll
    for (int j = 0; j < 16; ++j) {
        int idx = tid + j * 512;
        if (idx < n_e) {
            int e = e0 + idx;
            int r = ei[e];
            int c = ei[N_EDGES + e];
            int dst = dir ? r : c;
            int src = dir ? c : r;
            int b = dst >> BIN_SHIFT;
            binv[j] = b;
            rankv[j] = atomicAdd(&hist[b], 1);
            pay[j] = make_int2((int)(((unsigned)b << 22) | ((unsigned)(dst & 63) << 16) |
                                     (unsigned)src),
                               __float_as_int(ew[e]));
        } else {
            binv[j] = -1;
        }
    }
    __syncthreads();
    // pair-scan: 391 pairs cover 782 bins
    int ps = (tid < 391) ? (hist[2 * tid] + hist[2 * tid + 1]) : 0;
    sc[tid] = ps;
    __syncthreads();
    for (int off = 1; off < 512; off <<= 1) {
        int u = (tid >= off) ? sc[tid - off] : 0;
        __syncthreads();
        sc[tid] += u;
        __syncthreads();
    }
    if (tid < 391) {
        int pref = sc[tid] - ps;  // exclusive pair prefix
        lst[2 * tid] = pref;
        lst[2 * tid + 1] = pref + hist[2 * tid];
    }
    for (int i = tid; i < NBIN; i += 512)
        gStart[i] = cntG[(dir * NBIN + i) * NCHK + chunk];
    __syncthreads();
#pragma unroll
    for (int j = 0; j < 16; ++j)
        if (binv[j] >= 0) stg[lst[binv[j]] + rankv[j]] = pay[j];
    __syncthreads();
    for (int p = tid; p < n_e; p += 512) {
        int2 v2 = stg[p];
        int b = (int)(((unsigned)v2.x) >> 22);
        int gpos = gStart[b] + (p - lst[b]);
        binned[gpos] = make_int2(v2.x & 0x3FFFFF, v2.y);
    }
}

__device__ __forceinline__ void bin_range(const int* cntG, int b, int& lo, int& hi) {
    lo = cntG[b * NCHK];
    hi = (b + 1 < 2 * NBIN) ? cntG[(b + 1) * NCHK] : 2 * N_EDGES;
}

// 3. per-bin degrees + per-node counts (both dirs, one launch); linear stream.
__global__ __launch_bounds__(256) void bindeg_kernel(
    const int* __restrict__ cntG, const int2* __restrict__ binned,
    int* __restrict__ binCnt, float* __restrict__ ws_f) {
    __shared__ float wsum[64];
    __shared__ int cnt[64];
    int tid = threadIdx.x;
    int b = blockIdx.x;
    int dir = (b >= NBIN) ? 1 : 0;
    if (tid < 64) { wsum[tid] = 0.f; cnt[tid] = 0; }
    __syncthreads();
    int lo, hi;
    bin_range(cntG, b, lo, hi);
    for (int p = lo + tid; p < hi; p += 256) {
        int2 v = binned[p];
        int d = v.x >> 16;  // dstLocal (6 bits; bin bits stripped by partition)
        atomicAdd(&cnt[d], 1);
        atomicAdd(&wsum[d], __int_as_float(v.y));
    }
    __syncthreads();
    if (tid < 64) {
        binCnt[b * 64 + tid] = cnt[tid];
        int node = (b - dir * NBIN) * 64 + tid;
        if (node < N_NODES) {
            float s = wsum[tid];
            float* rdeg = ws_f + (dir == 0 ? WS_RDEG_IN : WS_RDEG_OUT);
            rdeg[node] = (s != 0.f) ? (1.f / s) : 0.f;
        }
    }
}

// 4. fused in-LDS binsort + register gather, both dirs, 256-thr blocks.
// B: coef = w*rdeg[src] computed here (off C's chain); s_edge = (src, coef).
// C: 32 groups x 8 lanes x 2 iterations, 4-way unrolled.
__global__ __launch_bounds__(256) void fgather_kernel(
    const ushort4* __restrict__ xsb, const int* __restrict__ cntG,
    const int* __restrict__ binCnt, const int2* __restrict__ binned,
    float* __restrict__ ws_f) {
    __shared__ int2 s_edge[FG_CAP];  // 20.5 KB -> 7 blocks/CU
    __shared__ int s_off[65];
    __shared__ int s_cur[64];
    __shared__ int sc[64];
    int tid = threadIdx.x;
    int b = blockIdx.x;
    int dir = (b >= NBIN) ? 1 : 0;
    int bin = b - dir * NBIN;

    // A: exclusive scan of 64 counts
    int v = (tid < 64) ? binCnt[b * 64 + tid] : 0;
    if (tid < 64) sc[tid] = v;
    __syncthreads();
    for (int off = 1; off < 64; off <<= 1) {
        int u = (tid < 64 && tid >= off) ? sc[tid - off] : 0;
        __syncthreads();
        if (tid < 64) sc[tid] += u;
        __syncthreads();
    }
    if (tid < 64) {
        s_off[tid] = sc[tid] - v;
        s_cur[tid] = sc[tid] - v;
    }
    if (tid == 63) s_off[64] = sc[63];
    __syncthreads();

    // B: stream bin edges; fold rdeg into coef; scatter (src, coef) sorted
    const float* rdeg = ws_f + (dir == 0 ? WS_RDEG_OUT : WS_RDEG_IN);
    int lo, hi;
    bin_range(cntG, b, lo, hi);
    int n_e = hi - lo;
    for (int p = tid; p < n_e; p += 256) {
        int2 ev = binned[lo + p];
        int src = ev.x & 0xffff;
        float coef = __int_as_float(ev.y) * rdeg[src];
        int rk = atomicAdd(&s_cur[ev.x >> 16], 1);
        if (rk < FG_CAP) s_edge[rk] = make_int2(src, __float_as_int(coef));
    }
    __syncthreads();

    // C: register-accumulating gather, 4-way unrolled
    ushort4* outp = (ushort4*)(ws_f + (dir == 0 ? WS_TXO : WS_TXI));
    int lane = tid & 7;
#pragma unroll
    for (int it = 0; it < 2; ++it) {
        int nl = it * 32 + (tid >> 3);
        int p = s_off[nl], end = s_off[nl + 1];
        float4 acc = make_float4(0.f, 0.f, 0.f, 0.f);
        for (; p + 3 < end; p += 4) {
            int2 v0 = s_edge[p], v1 = s_edge[p + 1];
            int2 v2 = s_edge[p + 2], v3 = s_edge[p + 3];
            ushort4 a0 = xsb[v0.x * 8 + lane];
            ushort4 a1 = xsb[v1.x * 8 + lane];
            ushort4 a2 = xsb[v2.x * 8 + lane];
            ushort4 a3 = xsb[v3.x * 8 + lane];
            float c0 = __int_as_float(v0.y), c1 = __int_as_float(v1.y);
            float c2 = __int_as_float(v2.y), c3 = __int_as_float(v3.y);
            acc.x += c0 * bf2f(a0.x) + c1 * bf2f(a1.x) + c2 * bf2f(a2.x) + c3 * bf2f(a3.x);
            acc.y += c0 * bf2f(a0.y) + c1 * bf2f(a1.y) + c2 * bf2f(a2.y) + c3 * bf2f(a3.y);
            acc.z += c0 * bf2f(a0.z) + c1 * bf2f(a1.z) + c2 * bf2f(a2.z) + c3 * bf2f(a3.z);
            acc.w += c0 * bf2f(a0.w) + c1 * bf2f(a1.w) + c2 * bf2f(a2.w) + c3 * bf2f(a3.w);
        }
        for (; p < end; ++p) {
            int2 v0 = s_edge[p];
            float c0 = __int_as_float(v0.y);
            ushort4 a = xsb[v0.x * 8 + lane];
            acc.x += c0 * bf2f(a.x);
            acc.y += c0 * bf2f(a.y);
            acc.z += c0 * bf2f(a.z);
            acc.w += c0 * bf2f(a.w);
        }
        int node = bin * 64 + nl;
        if (node < N_NODES) {
            ushort4 o;
            o.x = f2bf(acc.x); o.y = f2bf(acc.y);
            o.z = f2bf(acc.z); o.w = f2bf(acc.w);
            outp[node * 8 + lane] = o;
        }
    }
}

// 5. Dense epilogue via bf16 MFMA. x staged from the bf16 xsb copy (raw
// int4, L2-hot) -- bit-identical to converting fp32 x here.
// Per block: C[64 x 128 (z|h)] = A[64x96]_bf16 x B[96x128]_bf16 + bias.
// A-frag: A[m=lane&15][k=quad*8+j]; B-frag: B[k=quad*8+j][n=lane&15];
// C/D: col=lane&15, row=quad*4+reg (m89/m91-verified).
#define DN_GROUP 64
#define DN_BLOCKS ((N_NODES + DN_GROUP - 1) / DN_GROUP)  // 782
__global__ __launch_bounds__(256) void dense_kernel(
    const int4* __restrict__ xsb4,
    const int4* __restrict__ txo_b, const int4* __restrict__ txi_b,
    const unsigned short* __restrict__ wbf,
    const float* __restrict__ bz, const float* __restrict__ bh,
    const float* __restrict__ Wlin, const float* __restrict__ blin,
    float* __restrict__ out) {
    __shared__ unsigned short sA[64 * 104];  // 13.0 KB
    __shared__ unsigned short sB[12288];     // 24.0 KB

    int tid = threadIdx.x;
    int lane = tid & 63, w = tid >> 6;
    int lm = lane & 15, quad = lane >> 4;

    for (int idx = tid; idx < 3072; idx += 256)
        *(ushort4*)&sB[idx * 4] = ((const ushort4*)wbf)[idx];

    int node0 = blockIdx.x * DN_GROUP;
    // x part: 64 nodes x 4 int4 (bf16, raw copy from xsb)
    for (int idx = tid; idx < 64 * 4; idx += 256) {
        int nl = idx >> 2, q = idx & 3;
        int node = node0 + nl;
        int4 v = (node < N_NODES) ? xsb4[node * 4 + q] : make_int4(0, 0, 0, 0);
        *(int4*)&sA[nl * 104 + q * 8] = v;
    }
    // Tx part: 64 nodes x (4+4) int4 raw bf16
    for (int idx = tid; idx < 64 * 8; idx += 256) {
        int nl = idx >> 3, q = idx & 7;
        int node = node0 + nl;
        int4 v = make_int4(0, 0, 0, 0);
        if (node < N_NODES)
            v = (q < 4) ? txo_b[node * 4 + q] : txi_b[node * 4 + (q - 4)];
        *(int4*)&sA[nl * 104 + 32 + q * 8] = v;
    }

    float bzv[4], bhv[4], wlv[4];
#pragma unroll
    for (int bn = 0; bn < 4; ++bn) {
        int o = lm + 16 * bn;
        bzv[bn] = bz[o]; bhv[bn] = bh[o]; wlv[bn] = Wlin[o];
    }
    float bl = blin[0];
    __syncthreads();

    f32x4 acc[8];
#pragma unroll
    for (int bn = 0; bn < 4; ++bn) {
        acc[bn]     = (f32x4){bzv[bn], bzv[bn], bzv[bn], bzv[bn]};
        acc[bn + 4] = (f32x4){bhv[bn], bhv[bn], bhv[bn], bhv[bn]};
    }
#pragma unroll
    for (int kk = 0; kk < 3; ++kk) {
        bf16x8 af = *(const bf16x8*)&sA[(w * 16 + lm) * 104 + kk * 32 + quad * 8];
#pragma unroll
        for (int bn = 0; bn < 8; ++bn) {
            bf16x8 bf = *(const bf16x8*)&sB[((kk * 8 + bn) * 64 + lane) * 8];
            acc[bn] = __builtin_amdgcn_mfma_f32_16x16x32_bf16(af, bf, acc[bn], 0, 0, 0);
        }
    }

    float partial[4] = {0.f, 0.f, 0.f, 0.f};
#pragma unroll
    for (int bn = 0; bn < 4; ++bn) {
#pragma unroll
        for (int reg = 0; reg < 4; ++reg) {
            float az = acc[bn][reg], ah = acc[bn + 4][reg];
            float z = 1.f / (1.f + __expf(-az));
            float ht = 1.f - 2.f / (__expf(2.f * ah) + 1.f);
            partial[reg] += fmaxf((1.f - z) * ht, 0.f) * wlv[bn];
        }
    }
#pragma unroll
    for (int reg = 0; reg < 4; ++reg) {
        float s = partial[reg];
        s += __shfl_xor(s, 1, 64);
        s += __shfl_xor(s, 2, 64);
        s += __shfl_xor(s, 4, 64);
        s += __shfl_xor(s, 8, 64);
        if (lm == 0) {
            int node = node0 + w * 16 + quad * 4 + reg;
            if (node < N_NODES) out[node] = s + bl;
        }
    }
}

extern "C" void kernel_launch(void* const* d_in, const int* in_sizes, int n_in,
                              void* d_out, int out_size, void* d_ws, size_t ws_size,
                              hipStream_t stream) {
    const float* x = (const float*)d_in[0];
    const int* ei = (const int*)d_in[1];
    const float* ew = (const float*)d_in[2];
    const float* Wz = (const float*)d_in[3];
    const float* bz = (const float*)d_in[4];
    // d_in[5]=Wr, d_in[6]=br dead: H0==0 makes the reset gate a no-op
    const float* Wh = (const float*)d_in[7];
    const float* bh = (const float*)d_in[8];
    const float* Wlin = (const float*)d_in[9];
    const float* blin = (const float*)d_in[10];
    float* out = (float*)d_out;
    float* wf = (float*)d_ws;
    int* wi = (int*)d_ws;
    int2* binned = (int2*)(wi + WS_BINNED);

    // 0. fused prep: hist (chunks, critical path) + wprep + xconv
    prep_kernel<<<PREP_BLOCKS, 256, 0, stream>>>(
        ei, Wz, Wh, (const float4*)x, wi + WS_CNTG,
        (unsigned short*)(wi + WS_WBF), (ushort4*)(wi + WS_XSB));
    // 1. exclusive scan of the (dir,bin,chunk) count matrix
    scan_partial_kernel<<<SCAN_BLOCKS, 256, 0, stream>>>(
        (const int4*)(wi + WS_CNTG), wi + WS_BLKSUM, CNTG_N4);
    scan_blocksum_kernel<<<1, 256, 0, stream>>>(wi + WS_BLKSUM, SCAN_BLOCKS);
    scan_final_kernel<<<SCAN_BLOCKS, 256, 0, stream>>>(
        (int4*)(wi + WS_CNTG), wi + WS_BLKSUM, CNTG_N4);
    // 2. coalesced partition (one block per dir x 8192-chunk; LDS re-staging)
    partition_kernel<<<2 * NCHK, 512, 0, stream>>>(ei, ew, wi + WS_CNTG, binned);
    // 3. per-bin degrees + saved node counts (both dirs, linear stream)
    bindeg_kernel<<<2 * NBIN, 256, 0, stream>>>(
        wi + WS_CNTG, binned, wi + WS_BINCNT, wf);
    // 4. fused binsort+gather, both dirs -> bf16 Tx_o / Tx_i
    fgather_kernel<<<2 * NBIN, 256, 0, stream>>>(
        (const ushort4*)(wi + WS_XSB), wi + WS_CNTG, wi + WS_BINCNT, binned, wf);
    // 5. MFMA dense epilogue (all-bf16 inputs)
    dense_kernel<<<DN_BLOCKS, 256, 0, stream>>>(
        (const int4*)(wi + WS_XSB), (const int4*)(wi + WS_TXO),
        (const int4*)(wi + WS_TXI), (const unsigned short*)(wi + WS_WBF),
        bz, bh, Wlin, blin, out);
}